// Round 5
// baseline (68.709 us; speedup 1.0000x reference)
//
#include <hip/hip_runtime.h>

// B=32, H=W=512, C=3 toroidal 3x3 uniform depthwise avg + per-pixel quadratic forms.
#define HH 512
#define ROW4 384            // float4 per image row (512*3/4)  -- NOT a power of two!
#define RPW 8               // output rows per wave
#define EPS 0.1f

__global__ __launch_bounds__(256, 4)
void gnllt_kernel(const float* __restrict__ xin,
                  const float* __restrict__ A,
                  const float* __restrict__ Bm,
                  const float* __restrict__ Cm,
                  const float* __restrict__ bias,
                  const float* __restrict__ wk,
                  float* __restrict__ outp)
{
    const int lane  = threadIdx.x & 63;
    const int wsub  = threadIdx.x >> 6;
    const int wid   = (blockIdx.x << 2) | wsub;
    const int strip = wid & 1;            // two 256-px strips per row
    const int grp   = wid >> 1;           // 0..2047
    const int img   = grp >> 6;           // 0..31
    const int h0    = (grp & 63) * RPW;   // 0..504

    const int laneM1 = (lane + 63) & 63;
    const int laneP1 = (lane + 1) & 63;
    const bool isL0  = (lane == 0);
    const bool isL63 = (lane == 63);

    const int cb = strip * 192 + 3 * lane;   // own first f4 (0..381)
    // Wave-uniform halo f4 indices, explicit wrap (384 is NOT pow2 — no & trick):
    const int cL = strip ? 191 : 383;        // f4 holding row floats [base-4 .. base-1]
    const int cR = strip ? 0   : 192;        // f4 holding row floats [base+768 .. +771]

    // Uniform parameter loads; fold eps*wv^2 into quad coeffs, eps into bias.
    const float wv = wk[0];
    const float qs = EPS * wv * wv;
    const float qa00 = qs*A[0],  qa11 = qs*A[4],  qa22 = qs*A[8];
    const float qa01 = qs*(A[1]+A[3]),  qa02 = qs*(A[2]+A[6]),  qa12 = qs*(A[5]+A[7]);
    const float qb00 = qs*Bm[0], qb11 = qs*Bm[4], qb22 = qs*Bm[8];
    const float qb01 = qs*(Bm[1]+Bm[3]), qb02 = qs*(Bm[2]+Bm[6]), qb12 = qs*(Bm[5]+Bm[7]);
    const float qc00 = qs*Cm[0], qc11 = qs*Cm[4], qc22 = qs*Cm[8];
    const float qc01 = qs*(Cm[1]+Cm[3]), qc02 = qs*(Cm[2]+Cm[6]), qc12 = qs*(Cm[5]+Cm[7]);
    const float bi0 = EPS*bias[0], bi1 = EPS*bias[1], bi2 = EPS*bias[2];

    const float4* x4 = (const float4*)xin;
    float4*       o4 = (float4*)outp;
    const size_t  ib = (size_t)img * (HH * ROW4);

    __shared__ float4 obuf[4][192];       // wave-private output transpose slices
    float4* ob = obuf[wsub];

    float hs[3][12];      // rolling hsum rows, compile-time phase indices
    float raws[2][12];    // rolling raw rows

    // Load row (h0+j), compute horizontal channel-sums into hsd, opt. save raw.
    auto dorow = [&](int j, float* hsd, float* rawd) {
        const float4* rp = x4 + ib + (size_t)((h0 + j + HH) & (HH - 1)) * ROW4;
        const float4 Fa = rp[cb], Fb = rp[cb + 1], Fc = rp[cb + 2];
        const float4 LH = rp[cL], RH = rp[cR];   // wave-uniform broadcasts
        const float o0=Fa.x,o1=Fa.y,o2=Fa.z,o3=Fa.w,
                    p0=Fb.x,p1=Fb.y,p2=Fb.z,p3=Fb.w,
                    q0=Fc.x,q1=Fc.y,q2=Fc.z,q3=Fc.w;
        // halos from neighbor lanes (wave-edge lanes patched from broadcasts)
        float l0 = __shfl(q1, laneM1, 64);
        float l1 = __shfl(q2, laneM1, 64);
        float l2 = __shfl(q3, laneM1, 64);
        float r0 = __shfl(o0, laneP1, 64);
        float r1 = __shfl(o1, laneP1, 64);
        float r2 = __shfl(o2, laneP1, 64);
        l0 = isL0  ? LH.y : l0;  l1 = isL0  ? LH.z : l1;  l2 = isL0  ? LH.w : l2;
        r0 = isL63 ? RH.x : r0;  r1 = isL63 ? RH.y : r1;  r2 = isL63 ? RH.z : r2;
        hsd[0] = l0 + o0 + o3;  hsd[1]  = l1 + o1 + p0;  hsd[2]  = l2 + o2 + p1;
        hsd[3] = o0 + o3 + p2;  hsd[4]  = o1 + p0 + p3;  hsd[5]  = o2 + p1 + q0;
        hsd[6] = o3 + p2 + q1;  hsd[7]  = p0 + p3 + q2;  hsd[8]  = p1 + q0 + q3;
        hsd[9] = p2 + q1 + r0;  hsd[10] = p3 + q2 + r1;  hsd[11] = q0 + q3 + r2;
        if (rawd) {
            rawd[0]=o0; rawd[1]=o1; rawd[2]=o2;  rawd[3]=o3;
            rawd[4]=p0; rawd[5]=p1; rawd[6]=p2;  rawd[7]=p3;
            rawd[8]=q0; rawd[9]=q1; rawd[10]=q2; rawd[11]=q3;
        }
    };

    // Prime rows h0-1, h0
    dorow(-1, hs[0], nullptr);
    dorow(0,  hs[1], raws[0]);

    #pragma unroll
    for (int i = 0; i < RPW; ++i) {
        dorow(i + 1, hs[(i + 2) % 3], raws[(i + 1) & 1]);

        const float* hm  = hs[i % 3];
        const float* hc  = hs[(i + 1) % 3];
        const float* hp  = hs[(i + 2) % 3];
        const float* raw = raws[i & 1];

        float of[12];
        #pragma unroll
        for (int j = 0; j < 4; ++j) {
            const float s0 = hm[3*j+0] + hc[3*j+0] + hp[3*j+0];
            const float s1 = hm[3*j+1] + hc[3*j+1] + hp[3*j+1];
            const float s2 = hm[3*j+2] + hc[3*j+2] + hp[3*j+2];
            const float p00 = s0*s0, p11 = s1*s1, p22 = s2*s2;
            const float p01 = s0*s1, p02 = s0*s2, p12 = s1*s2;
            of[3*j+0] = raw[3*j+0] + bi0 + qa00*p00 + qa11*p11 + qa22*p22
                                         + qa01*p01 + qa02*p02 + qa12*p12;
            of[3*j+1] = raw[3*j+1] + bi1 + qb00*p00 + qb11*p11 + qb22*p22
                                         + qb01*p01 + qb02*p02 + qb12*p12;
            of[3*j+2] = raw[3*j+2] + bi2 + qc00*p00 + qc11*p11 + qc22*p22
                                         + qc01*p01 + qc02*p02 + qc12*p12;
        }

        // Per-wave LDS transpose: 48B-stride writes (uniform bank coverage),
        // in-wave lgkmcnt fence, flat 16B-stride reads -> coalesced stores.
        ob[3*lane + 0] = make_float4(of[0], of[1], of[2],  of[3]);
        ob[3*lane + 1] = make_float4(of[4], of[5], of[6],  of[7]);
        ob[3*lane + 2] = make_float4(of[8], of[9], of[10], of[11]);
        asm volatile("s_waitcnt lgkmcnt(0)" ::: "memory");
        const float4 s0 = ob[lane], s1 = ob[lane + 64], s2 = ob[lane + 128];

        float4* op = o4 + ib + (size_t)(h0 + i) * ROW4 + strip * 192;
        op[lane]       = s0;
        op[lane + 64]  = s1;
        op[lane + 128] = s2;
    }
}

extern "C" void kernel_launch(void* const* d_in, const int* in_sizes, int n_in,
                              void* d_out, int out_size, void* d_ws, size_t ws_size,
                              hipStream_t stream) {
    const float* x    = (const float*)d_in[0];
    const float* A    = (const float*)d_in[1];
    const float* Bm   = (const float*)d_in[2];
    const float* Cm   = (const float*)d_in[3];
    const float* bias = (const float*)d_in[4];
    const float* wk   = (const float*)d_in[5];
    float* out = (float*)d_out;

    // 32 imgs x 64 row-groups x 2 strips = 4096 waves = 1024 blocks of 4 waves
    dim3 grid(1024);
    dim3 block(256);
    gnllt_kernel<<<grid, block, 0, stream>>>(x, A, Bm, Cm, bias, wk, out);
}

// Round 6
// 42.651 us; speedup vs baseline: 1.6109x; 1.6109x over previous
//
#include <hip/hip_runtime.h>

// B=32, H=W=512, C=3, toroidal 3x3 uniform depthwise avg + per-pixel quadratic forms.
#define HH 512
#define ROW4 384            // float4 per image row (512*3/4)
#define RPW 4               // rows per wave (doubled grid vs R3 for latency hiding)
#define EPS 0.1f

__device__ __forceinline__ void load_hsum(const float4* __restrict__ rp,
                                          const int* c, float* S, float* rawdst) {
    // g[m] = row[12*t - 4 + m], m = 0..19 (t = lane's first own f4 / 3)
    float4 F0 = rp[c[0]], F1 = rp[c[1]], F2 = rp[c[2]], F3 = rp[c[3]], F4 = rp[c[4]];
    float g[20] = {F0.x,F0.y,F0.z,F0.w, F1.x,F1.y,F1.z,F1.w, F2.x,F2.y,F2.z,F2.w,
                   F3.x,F3.y,F3.z,F3.w, F4.x,F4.y,F4.z,F4.w};
    // hsum for own 4 px, 3 ch: hs[3j+c] = x[px-1..px+1] channel sum
    #pragma unroll
    for (int q = 0; q < 12; ++q) S[q] = g[1+q] + g[4+q] + g[7+q];
    if (rawdst) {
        #pragma unroll
        for (int q = 0; q < 12; ++q) rawdst[q] = g[4+q];   // own 12 floats
    }
}

__global__ __launch_bounds__(256)
void gnllt_kernel(const float* __restrict__ xin,
                  const float* __restrict__ A,
                  const float* __restrict__ Bm,
                  const float* __restrict__ Cm,
                  const float* __restrict__ bias,
                  const float* __restrict__ wk,
                  float* __restrict__ outp)
{
    const int lane  = threadIdx.x & 63;
    const int wid   = (blockIdx.x << 2) | (threadIdx.x >> 6);
    const int strip = wid & 1;            // two 256-px strips per row
    const int grp   = wid >> 1;           // 0..4095
    const int img   = grp >> 7;           // 0..31  (128 row-groups per image)
    const int h0    = (grp & 127) * RPW;  // 0..508

    // Uniform parameter loads -> SGPRs. Fold eps * wv^2 into quad coeffs.
    const float wv = wk[0];
    const float qs = EPS * wv * wv;
    const float qa00 = qs*A[0],  qa11 = qs*A[4],  qa22 = qs*A[8];
    const float qa01 = qs*(A[1]+A[3]),  qa02 = qs*(A[2]+A[6]),  qa12 = qs*(A[5]+A[7]);
    const float qb00 = qs*Bm[0], qb11 = qs*Bm[4], qb22 = qs*Bm[8];
    const float qb01 = qs*(Bm[1]+Bm[3]), qb02 = qs*(Bm[2]+Bm[6]), qb12 = qs*(Bm[5]+Bm[7]);
    const float qc00 = qs*Cm[0], qc11 = qs*Cm[4], qc22 = qs*Cm[8];
    const float qc01 = qs*(Cm[1]+Cm[3]), qc02 = qs*(Cm[2]+Cm[6]), qc12 = qs*(Cm[5]+Cm[7]);
    const float bi0 = EPS*bias[0], bi1 = EPS*bias[1], bi2 = EPS*bias[2];

    const float4* x4 = (const float4*)xin;
    float4*       o4 = (float4*)outp;

    // f4-column indices for the 5 overlapping loads (wrap within row; 384 not pow2)
    const int cb = strip * 192 + 3 * lane;     // first own f4 in row
    int c[5];
    #pragma unroll
    for (int j = 0; j < 5; ++j) {
        int v = cb - 1 + j;
        if (v < 0)     v += ROW4;
        if (v >= ROW4) v -= ROW4;
        c[j] = v;
    }
    const size_t ib = (size_t)img * (HH * ROW4);

    float hs[3][12];    // rolling horizontal-sum rows (compile-time phase indices)
    float raw[12];      // raw row h (for output)
    float rawN[12];     // raw row h+1 in flight

    // Prime: rows h0-1 and h0
    load_hsum(x4 + ib + (size_t)((h0 + HH - 1) & (HH - 1)) * ROW4, c, hs[0], nullptr);
    load_hsum(x4 + ib + (size_t)h0 * ROW4,                         c, hs[1], raw);

    #pragma unroll
    for (int i = 0; i < RPW; ++i) {
        const int r = (h0 + 1 + i) & (HH - 1);
        load_hsum(x4 + ib + (size_t)r * ROW4, c, hs[(2 + i) % 3], rawN);

        const float* hm = hs[i % 3];
        const float* hc = hs[(i + 1) % 3];
        const float* hp = hs[(i + 2) % 3];

        float of[12];
        #pragma unroll
        for (int j = 0; j < 4; ++j) {
            const float s0 = hm[3*j+0] + hc[3*j+0] + hp[3*j+0];
            const float s1 = hm[3*j+1] + hc[3*j+1] + hp[3*j+1];
            const float s2 = hm[3*j+2] + hc[3*j+2] + hp[3*j+2];
            const float p00 = s0*s0, p11 = s1*s1, p22 = s2*s2;
            const float p01 = s0*s1, p02 = s0*s2, p12 = s1*s2;
            of[3*j+0] = raw[3*j+0] + bi0 + qa00*p00 + qa11*p11 + qa22*p22
                                        + qa01*p01 + qa02*p02 + qa12*p12;
            of[3*j+1] = raw[3*j+1] + bi1 + qb00*p00 + qb11*p11 + qb22*p22
                                        + qb01*p01 + qb02*p02 + qb12*p12;
            of[3*j+2] = raw[3*j+2] + bi2 + qc00*p00 + qc11*p11 + qc22*p22
                                        + qc01*p01 + qc02*p02 + qc12*p12;
        }

        float4* op = o4 + ib + (size_t)(h0 + i) * ROW4 + cb;
        op[0] = make_float4(of[0], of[1], of[2],  of[3]);
        op[1] = make_float4(of[4], of[5], of[6],  of[7]);
        op[2] = make_float4(of[8], of[9], of[10], of[11]);

        #pragma unroll
        for (int q = 0; q < 12; ++q) raw[q] = rawN[q];
    }
}

extern "C" void kernel_launch(void* const* d_in, const int* in_sizes, int n_in,
                              void* d_out, int out_size, void* d_ws, size_t ws_size,
                              hipStream_t stream) {
    const float* x    = (const float*)d_in[0];
    const float* A    = (const float*)d_in[1];
    const float* Bm   = (const float*)d_in[2];
    const float* Cm   = (const float*)d_in[3];
    const float* bias = (const float*)d_in[4];
    const float* wk   = (const float*)d_in[5];
    float* out = (float*)d_out;

    // 32 imgs x 128 row-groups x 2 strips = 8192 waves = 2048 blocks of 4 waves
    dim3 grid(2048);
    dim3 block(256);
    gnllt_kernel<<<grid, block, 0, stream>>>(x, A, Bm, Cm, bias, wk, out);
}